// Round 1
// baseline (622.568 us; speedup 1.0000x reference)
//
#include <hip/hip_runtime.h>

typedef __attribute__((ext_vector_type(8))) short short8;
typedef __attribute__((ext_vector_type(4))) float floatx4;

#define LOG2E 1.44269504088896340736f

__device__ __forceinline__ ushort f2bf(float f) {
  union { float f; unsigned u; } v; v.f = f;
  unsigned r = v.u + 0x7fffu + ((v.u >> 16) & 1u);
  return (ushort)(r >> 16);
}

// ---------------- Projection GEMM: Out[b,h,s,hd] (bf16) = (X @ W) * scale ---
// X: [8192,1024] fp32, W: [1024,1024] fp32.
__global__ __launch_bounds__(256) void k_proj(
    const float* __restrict__ X, const float* __restrict__ W,
    ushort* __restrict__ Out, float scale)
{
  __shared__ __align__(16) ushort As[128 * 40];
  __shared__ __align__(16) ushort Bs[128 * 40];
  const int tid = threadIdx.x;
  const int lane = tid & 63, w = tid >> 6;
  const int wm = w >> 1, wn = w & 1;
  const int lr = lane & 15, lk = lane >> 4;
  const int m0 = blockIdx.y * 128, n0 = blockIdx.x * 128;

  const int ar = tid >> 1, ac = (tid & 1) * 16;   // A stage: row, col16
  const int bk = tid >> 3, bn = (tid & 7) * 16;   // B stage: k-row, n16

  floatx4 acc[4][4] = {};

  for (int kt = 0; kt < 1024; kt += 32) {
    { // stage A tile -> As[row][k], convert fp32->bf16
      const float* src = X + (size_t)(m0 + ar) * 1024 + kt + ac;
      float va[16];
      #pragma unroll
      for (int i = 0; i < 4; i++) ((float4*)va)[i] = ((const float4*)src)[i];
      unsigned up[8];
      #pragma unroll
      for (int i = 0; i < 8; i++)
        up[i] = (unsigned)f2bf(va[2*i]) | ((unsigned)f2bf(va[2*i+1]) << 16);
      ushort* dst = &As[ar * 40 + ac];
      ((uint4*)dst)[0] = ((uint4*)up)[0];
      ((uint4*)dst)[1] = ((uint4*)up)[1];
    }
    { // stage B tile transposed -> Bs[n][k]
      const float* src = W + (size_t)(kt + bk) * 1024 + n0 + bn;
      float vb[16];
      #pragma unroll
      for (int i = 0; i < 4; i++) ((float4*)vb)[i] = ((const float4*)src)[i];
      #pragma unroll
      for (int i = 0; i < 16; i++) Bs[(bn + i) * 40 + bk] = f2bf(vb[i]);
    }
    __syncthreads();
    short8 a[4], bf[4];
    #pragma unroll
    for (int f = 0; f < 4; f++)
      a[f] = *(const short8*)&As[(wm*64 + f*16 + lr) * 40 + lk*8];
    #pragma unroll
    for (int f = 0; f < 4; f++)
      bf[f] = *(const short8*)&Bs[(wn*64 + f*16 + lr) * 40 + lk*8];
    #pragma unroll
    for (int i = 0; i < 4; i++)
      #pragma unroll
      for (int j = 0; j < 4; j++)
        acc[i][j] = __builtin_amdgcn_mfma_f32_16x16x32_bf16(a[i], bf[j], acc[i][j], 0, 0, 0);
    __syncthreads();
  }
  // epilogue: write bf16 to [B,H,S,HD]
  #pragma unroll
  for (int i = 0; i < 4; i++) {
    #pragma unroll
    for (int j = 0; j < 4; j++) {
      const int n = n0 + wn*64 + j*16 + lr;
      const int h = n >> 6, hd = n & 63;
      #pragma unroll
      for (int r = 0; r < 4; r++) {
        const int m = m0 + wm*64 + i*16 + lk*4 + r;
        const int bb = m >> 11, s = m & 2047;
        Out[(((size_t)(bb*16 + h)) * 2048 + s) * 64 + hd] = f2bf(acc[i][j][r] * scale);
      }
    }
  }
}

// ---------------- Output GEMM: Out[m,n] (fp32) = AO(bf16) @ Wo(fp32->bf16) --
__global__ __launch_bounds__(256) void k_out(
    const ushort* __restrict__ A, const float* __restrict__ W,
    float* __restrict__ Out)
{
  __shared__ __align__(16) ushort As[128 * 40];
  __shared__ __align__(16) ushort Bs[128 * 40];
  const int tid = threadIdx.x;
  const int lane = tid & 63, w = tid >> 6;
  const int wm = w >> 1, wn = w & 1;
  const int lr = lane & 15, lk = lane >> 4;
  const int m0 = blockIdx.y * 128, n0 = blockIdx.x * 128;

  const int ar = tid >> 1, ac = (tid & 1) * 16;
  const int bk = tid >> 3, bn = (tid & 7) * 16;

  floatx4 acc[4][4] = {};

  for (int kt = 0; kt < 1024; kt += 32) {
    {
      const ushort* src = A + (size_t)(m0 + ar) * 1024 + kt + ac;
      ushort* dst = &As[ar * 40 + ac];
      ((uint4*)dst)[0] = ((const uint4*)src)[0];
      ((uint4*)dst)[1] = ((const uint4*)src)[1];
    }
    {
      const float* src = W + (size_t)(kt + bk) * 1024 + n0 + bn;
      float vb[16];
      #pragma unroll
      for (int i = 0; i < 4; i++) ((float4*)vb)[i] = ((const float4*)src)[i];
      #pragma unroll
      for (int i = 0; i < 16; i++) Bs[(bn + i) * 40 + bk] = f2bf(vb[i]);
    }
    __syncthreads();
    short8 a[4], bf[4];
    #pragma unroll
    for (int f = 0; f < 4; f++)
      a[f] = *(const short8*)&As[(wm*64 + f*16 + lr) * 40 + lk*8];
    #pragma unroll
    for (int f = 0; f < 4; f++)
      bf[f] = *(const short8*)&Bs[(wn*64 + f*16 + lr) * 40 + lk*8];
    #pragma unroll
    for (int i = 0; i < 4; i++)
      #pragma unroll
      for (int j = 0; j < 4; j++)
        acc[i][j] = __builtin_amdgcn_mfma_f32_16x16x32_bf16(a[i], bf[j], acc[i][j], 0, 0, 0);
    __syncthreads();
  }
  #pragma unroll
  for (int i = 0; i < 4; i++) {
    #pragma unroll
    for (int j = 0; j < 4; j++) {
      const int n = n0 + wn*64 + j*16 + lr;
      #pragma unroll
      for (int r = 0; r < 4; r++) {
        const int m = m0 + wm*64 + i*16 + lk*4 + r;
        Out[(size_t)m * 1024 + n] = acc[i][j][r];
      }
    }
  }
}

// ---------------- Flash attention: per (b,h), 64 q-rows per block ----------
// Q,K,V: [B,H,S,HD] bf16 (Q pre-scaled by 1/8). AO out: [B,S,D] bf16.
__global__ __launch_bounds__(256) void k_attn(
    const ushort* __restrict__ Q, const ushort* __restrict__ K,
    const ushort* __restrict__ V, const int* __restrict__ amask,
    ushort* __restrict__ AO)
{
  const int LDK = 72;
  __shared__ __align__(16) ushort Kl[64 * 72];
  __shared__ __align__(16) ushort Vt[64 * 72];
  __shared__ __align__(16) ushort Pl[4][16 * 72];

  const int tid = threadIdx.x;
  const int lane = tid & 63, w = tid >> 6;
  const int lr = lane & 15, lk = lane >> 4;
  const int bh = blockIdx.y;
  const int b = bh >> 4, h = bh & 15;
  const int q0 = blockIdx.x * 64;

  const ushort* Qbh = Q + (size_t)bh * 2048 * 64;
  const ushort* Kbh = K + (size_t)bh * 2048 * 64;
  const ushort* Vbh = V + (size_t)bh * 2048 * 64;

  // Q fragments for this wave's 16 rows (A-layout: row=lr, k=lk*8+j)
  const int qrow = q0 + w * 16 + lr;
  short8 aq0 = *(const short8*)(Qbh + (size_t)qrow * 64 + lk * 8);
  short8 aq1 = *(const short8*)(Qbh + (size_t)qrow * 64 + 32 + lk * 8);

  floatx4 o[4] = {};
  float mrow[4] = {-1e30f, -1e30f, -1e30f, -1e30f};
  float lrow[4] = {0.f, 0.f, 0.f, 0.f};

  const int sr = tid >> 2, sc = (tid & 3) * 16;  // staging: row, col16
  const int ntiles = blockIdx.x + 1;

  for (int t = 0; t < ntiles; t++) {
    const int kv0 = t * 64;
    __syncthreads();
    { // stage K as-is, V transposed
      const ushort* ks = Kbh + (size_t)(kv0 + sr) * 64 + sc;
      ((uint4*)&Kl[sr * LDK + sc])[0] = ((const uint4*)ks)[0];
      ((uint4*)&Kl[sr * LDK + sc])[1] = ((const uint4*)ks)[1];
      const ushort* vs = Vbh + (size_t)(kv0 + sr) * 64 + sc;
      ushort vv[16];
      ((uint4*)vv)[0] = ((const uint4*)vs)[0];
      ((uint4*)vv)[1] = ((const uint4*)vs)[1];
      #pragma unroll
      for (int i = 0; i < 16; i++) Vt[(sc + i) * LDK + sr] = vv[i];
    }
    __syncthreads();

    // S = Q K^T  (rows=q, cols=kv)
    floatx4 sa[4] = {};
    #pragma unroll
    for (int f = 0; f < 4; f++) {
      short8 b0 = *(const short8*)&Kl[(f*16 + lr) * LDK + lk*8];
      short8 b1 = *(const short8*)&Kl[(f*16 + lr) * LDK + 32 + lk*8];
      sa[f] = __builtin_amdgcn_mfma_f32_16x16x32_bf16(aq0, b0, sa[f], 0, 0, 0);
      sa[f] = __builtin_amdgcn_mfma_f32_16x16x32_bf16(aq1, b1, sa[f], 0, 0, 0);
    }

    // masking: key mask always, causal only on diagonal tile
    const bool diag = (t == ntiles - 1);
    #pragma unroll
    for (int f = 0; f < 4; f++) {
      const int kv = kv0 + f*16 + lr;
      const bool kvalid = amask[b * 2048 + kv] != 0;
      #pragma unroll
      for (int r = 0; r < 4; r++) {
        const int q = q0 + w*16 + lk*4 + r;
        if (!kvalid || (diag && kv > q)) sa[f][r] = -1e30f;
      }
    }

    // online softmax (row = lk*4+r, spread over 16 lanes lr)
    float scl[4];
    #pragma unroll
    for (int r = 0; r < 4; r++) {
      float mx = fmaxf(fmaxf(sa[0][r], sa[1][r]), fmaxf(sa[2][r], sa[3][r]));
      mx = fmaxf(mx, __shfl_xor(mx, 1, 64));
      mx = fmaxf(mx, __shfl_xor(mx, 2, 64));
      mx = fmaxf(mx, __shfl_xor(mx, 4, 64));
      mx = fmaxf(mx, __shfl_xor(mx, 8, 64));
      const float mnew = fmaxf(mrow[r], mx);
      scl[r] = exp2f((mrow[r] - mnew) * LOG2E);
      mrow[r] = mnew;
    }
    float rsum[4] = {0.f, 0.f, 0.f, 0.f};
    #pragma unroll
    for (int f = 0; f < 4; f++)
      #pragma unroll
      for (int r = 0; r < 4; r++) {
        float p = exp2f((sa[f][r] - mrow[r]) * LOG2E);
        sa[f][r] = p;
        rsum[r] += p;
      }
    #pragma unroll
    for (int r = 0; r < 4; r++) {
      rsum[r] += __shfl_xor(rsum[r], 1, 64);
      rsum[r] += __shfl_xor(rsum[r], 2, 64);
      rsum[r] += __shfl_xor(rsum[r], 4, 64);
      rsum[r] += __shfl_xor(rsum[r], 8, 64);
      lrow[r] = lrow[r] * scl[r] + rsum[r];
    }
    #pragma unroll
    for (int f = 0; f < 4; f++)
      #pragma unroll
      for (int r = 0; r < 4; r++) o[f][r] *= scl[r];

    // P -> LDS (C-layout write), then consume as A-layout
    #pragma unroll
    for (int f = 0; f < 4; f++)
      #pragma unroll
      for (int r = 0; r < 4; r++)
        Pl[w][(lk*4 + r) * LDK + f*16 + lr] = f2bf(sa[f][r]);
    __syncthreads();

    short8 ap0 = *(const short8*)&Pl[w][lr * LDK + lk*8];
    short8 ap1 = *(const short8*)&Pl[w][lr * LDK + 32 + lk*8];
    #pragma unroll
    for (int f = 0; f < 4; f++) {
      short8 bv0 = *(const short8*)&Vt[(f*16 + lr) * LDK + lk*8];
      short8 bv1 = *(const short8*)&Vt[(f*16 + lr) * LDK + 32 + lk*8];
      o[f] = __builtin_amdgcn_mfma_f32_16x16x32_bf16(ap0, bv0, o[f], 0, 0, 0);
      o[f] = __builtin_amdgcn_mfma_f32_16x16x32_bf16(ap1, bv1, o[f], 0, 0, 0);
    }
  }

  // epilogue: normalize, write AO[b, s, h*64+hd] bf16
  #pragma unroll
  for (int r = 0; r < 4; r++) {
    const float inv = lrow[r] > 0.f ? 1.0f / lrow[r] : 0.f;
    const int s = q0 + w*16 + lk*4 + r;
    const size_t base = ((size_t)b * 2048 + s) * 1024 + h * 64;
    #pragma unroll
    for (int f = 0; f < 4; f++)
      AO[base + f*16 + lr] = f2bf(o[f][r] * inv);
  }
}

extern "C" void kernel_launch(void* const* d_in, const int* in_sizes, int n_in,
                              void* d_out, int out_size, void* d_ws, size_t ws_size,
                              hipStream_t stream) {
  const float* x    = (const float*)d_in[0];
  const int*   amask= (const int*)d_in[1];
  const float* Wq   = (const float*)d_in[2];
  const float* Wk   = (const float*)d_in[3];
  const float* Wv   = (const float*)d_in[4];
  const float* Wo   = (const float*)d_in[5];
  float* out = (float*)d_out;

  const size_t NEL = (size_t)4 * 2048 * 1024;  // 8,388,608 elems per tensor
  ushort* Q  = (ushort*)d_ws;
  ushort* K  = Q + NEL;
  ushort* V  = K + NEL;
  ushort* AO = V + NEL;

  dim3 blk(256);
  dim3 gProj(8, 64);   // N/128, M/128
  k_proj<<<gProj, blk, 0, stream>>>(x, Wq, Q, 0.125f);
  k_proj<<<gProj, blk, 0, stream>>>(x, Wk, K, 1.0f);
  k_proj<<<gProj, blk, 0, stream>>>(x, Wv, V, 1.0f);

  dim3 gAttn(32, 64);  // S/64, B*H
  k_attn<<<gAttn, blk, 0, stream>>>(Q, K, V, amask, AO);

  dim3 gOut(8, 64);
  k_out<<<gOut, blk, 0, stream>>>(AO, Wo, out);
}

// Round 3
// 378.679 us; speedup vs baseline: 1.6441x; 1.6441x over previous
//
#include <hip/hip_runtime.h>

typedef __attribute__((ext_vector_type(8))) short short8;
typedef __attribute__((ext_vector_type(4))) float floatx4;
typedef __attribute__((address_space(3))) void lvoid;
typedef const __attribute__((address_space(1))) void gvoid;

#define LOG2E 1.44269504088896340736f

__device__ __forceinline__ ushort f2bf(float f) {
  union { float f; unsigned u; } v; v.f = f;
  unsigned r = v.u + 0x7fffu + ((v.u >> 16) & 1u);
  return (ushort)(r >> 16);
}

__device__ __forceinline__ void gld16(const void* g, void* l) {
  __builtin_amdgcn_global_load_lds((gvoid*)g, (lvoid*)l, 16, 0, 0);
}

// ---------------- prep: X fp32 -> bf16 -------------------------------------
__global__ __launch_bounds__(256) void k_prep_x(const float* __restrict__ X,
                                                ushort* __restrict__ Xb) {
  const size_t i = ((size_t)blockIdx.x * 256 + threadIdx.x) * 8;
  float4 v0 = *(const float4*)(X + i);
  float4 v1 = *(const float4*)(X + i + 4);
  ushort u[8] = {f2bf(v0.x), f2bf(v0.y), f2bf(v0.z), f2bf(v0.w),
                 f2bf(v1.x), f2bf(v1.y), f2bf(v1.z), f2bf(v1.w)};
  *(uint4*)(Xb + i) = *(uint4*)u;
}

// ---------------- prep: W fp32 [K][N] -> bf16 transposed [N][K] ------------
__global__ __launch_bounds__(256) void k_prep_wt(
    const float* __restrict__ W0, const float* __restrict__ W1,
    const float* __restrict__ W2, const float* __restrict__ W3,
    ushort* __restrict__ T0, ushort* __restrict__ T1,
    ushort* __restrict__ T2, ushort* __restrict__ T3) {
  __shared__ ushort T[64][66];
  const int z = blockIdx.z;
  const float* W = z == 0 ? W0 : (z == 1 ? W1 : (z == 2 ? W2 : W3));
  ushort* Wt = z == 0 ? T0 : (z == 1 ? T1 : (z == 2 ? T2 : T3));
  const int kb = blockIdx.x * 64, nb = blockIdx.y * 64;
  const int t = threadIdx.x, r = t >> 2, c0 = (t & 3) * 16;
  const float* src = W + (size_t)(kb + r) * 1024 + nb + c0;
  #pragma unroll
  for (int i = 0; i < 4; i++) {
    float4 a = ((const float4*)src)[i];
    T[r][c0 + i*4 + 0] = f2bf(a.x); T[r][c0 + i*4 + 1] = f2bf(a.y);
    T[r][c0 + i*4 + 2] = f2bf(a.z); T[r][c0 + i*4 + 3] = f2bf(a.w);
  }
  __syncthreads();
  ushort u[16];
  #pragma unroll
  for (int j = 0; j < 16; j++) u[j] = T[c0 + j][r];
  ushort* dst = Wt + (size_t)(nb + r) * 1024 + kb + c0;
  ((uint4*)dst)[0] = ((uint4*)u)[0];
  ((uint4*)dst)[1] = ((uint4*)u)[1];
}

// ---------------- GEMM loop (macro, templated B staging) -------------------
// A [M][1024] bf16 row-major via gld16 + chunk-XOR swizzle.
// PREPPED: B [N][1024] bf16 row-major via gld16 + swizzle.
// !PREPPED: B from fp32 W [K][N], register-staged transposed into padded LDS.
#define GEMM_LOOP(Aptr, BTptr, BFptr)                                          \
  constexpr int LDB = PREPPED ? 32 : 40;                                       \
  __shared__ __align__(16) ushort As[128 * 32];                                \
  __shared__ __align__(16) ushort Bs[128 * LDB];                               \
  const int tid = threadIdx.x, l = tid & 63, w = tid >> 6;                     \
  const int wm = w >> 1, wn = w & 1, lr = l & 15, lk = l >> 4;                 \
  const int m0 = blockIdx.y * 128, n0 = blockIdx.x * 128;                      \
  const int srow = l >> 2;                                                     \
  const int scol = ((l & 3) ^ ((l >> 3) & 3)) * 8;                             \
  const int c0 = w * 2;                                                        \
  const int xchunk = (lk ^ ((lr >> 1) & 3)) * 8;                               \
  const int bk = tid >> 3, bn = (tid & 7) * 16;                                \
  floatx4 acc[4][4] = {};                                                      \
  for (int kt = 0; kt < 1024; kt += 32) {                                      \
    __syncthreads();                                                           \
    _Pragma("unroll")                                                          \
    for (int i = 0; i < 2; i++) {                                              \
      const int c = c0 + i;                                                    \
      gld16(Aptr + (size_t)(m0 + c*16 + srow) * 1024 + kt + scol, &As[c*512]); \
      if constexpr (PREPPED)                                                   \
        gld16(BTptr + (size_t)(n0 + c*16 + srow) * 1024 + kt + scol,           \
              &Bs[c*512]);                                                     \
    }                                                                          \
    if constexpr (!PREPPED) {                                                  \
      const float* src = BFptr + (size_t)(kt + bk) * 1024 + n0 + bn;           \
      float vb[16];                                                            \
      _Pragma("unroll")                                                        \
      for (int i = 0; i < 4; i++) ((float4*)vb)[i] = ((const float4*)src)[i];  \
      _Pragma("unroll")                                                        \
      for (int i = 0; i < 16; i++) Bs[(bn + i) * 40 + bk] = f2bf(vb[i]);       \
    }                                                                          \
    __syncthreads();                                                           \
    short8 af[4], bfr[4];                                                      \
    _Pragma("unroll")                                                          \
    for (int f = 0; f < 4; f++) {                                              \
      af[f] = *(const short8*)&As[(wm*64 + f*16 + lr) * 32 + xchunk];          \
      if constexpr (PREPPED)                                                   \
        bfr[f] = *(const short8*)&Bs[(wn*64 + f*16 + lr) * 32 + xchunk];       \
      else                                                                     \
        bfr[f] = *(const short8*)&Bs[(wn*64 + f*16 + lr) * 40 + lk*8];         \
    }                                                                          \
    _Pragma("unroll")                                                          \
    for (int i = 0; i < 4; i++)                                                \
      _Pragma("unroll")                                                        \
      for (int j = 0; j < 4; j++)                                              \
        acc[i][j] = __builtin_amdgcn_mfma_f32_16x16x32_bf16(af[i], bfr[j],     \
                                                            acc[i][j], 0,0,0);\
  }

// Projection GEMM (z = 0,1,2 -> Q,K,V); writes bf16 [B,H,S,HD], Q scaled 1/8.
template <bool PREPPED>
__global__ __launch_bounds__(256) void k_proj(
    const ushort* __restrict__ Xb,
    const ushort* __restrict__ Wtq, const ushort* __restrict__ Wtk,
    const ushort* __restrict__ Wtv,
    const float* __restrict__ Wfq, const float* __restrict__ Wfk,
    const float* __restrict__ Wfv,
    ushort* __restrict__ Qo, ushort* __restrict__ Ko, ushort* __restrict__ Vo)
{
  const int z = blockIdx.z;
  const ushort* Bt = PREPPED ? (z == 0 ? Wtq : (z == 1 ? Wtk : Wtv)) : nullptr;
  const float*  Bf = PREPPED ? nullptr : (z == 0 ? Wfq : (z == 1 ? Wfk : Wfv));
  ushort* Out = z == 0 ? Qo : (z == 1 ? Ko : Vo);
  const float scale = z == 0 ? 0.125f : 1.0f;
  GEMM_LOOP(Xb, Bt, Bf)
  #pragma unroll
  for (int i = 0; i < 4; i++) {
    #pragma unroll
    for (int j = 0; j < 4; j++) {
      const int n = n0 + wn*64 + j*16 + lr;
      const int h = n >> 6, hd = n & 63;
      #pragma unroll
      for (int r = 0; r < 4; r++) {
        const int m = m0 + wm*64 + i*16 + lk*4 + r;
        const int bb = m >> 11, s = m & 2047;
        Out[(((size_t)(bb*16 + h)) * 2048 + s) * 64 + hd] = f2bf(acc[i][j][r] * scale);
      }
    }
  }
}

// Output GEMM: fp32 out [8192][1024] = AO(bf16) @ Wo
template <bool PREPPED>
__global__ __launch_bounds__(256) void k_out(
    const ushort* __restrict__ A, const ushort* __restrict__ Wt,
    const float* __restrict__ Wf, float* __restrict__ Out)
{
  GEMM_LOOP(A, Wt, Wf)
  #pragma unroll
  for (int i = 0; i < 4; i++) {
    #pragma unroll
    for (int j = 0; j < 4; j++) {
      const int n = n0 + wn*64 + j*16 + lr;
      #pragma unroll
      for (int r = 0; r < 4; r++) {
        const int m = m0 + wm*64 + i*16 + lk*4 + r;
        Out[(size_t)m * 1024 + n] = acc[i][j][r];
      }
    }
  }
}

// ---------------- Flash attention, paired q-tiles {p, 31-p} ----------------
// K staged via gld16 (chunk-XOR swizzled source), V via register transpose.
__global__ __launch_bounds__(256) void k_attn(
    const ushort* __restrict__ Q, const ushort* __restrict__ K,
    const ushort* __restrict__ V, const int* __restrict__ amask,
    ushort* __restrict__ AO)
{
  __shared__ __align__(16) ushort Kl[64 * 64];     // XOR-swizzled, no pad
  __shared__ __align__(16) ushort Vt[64 * 72];     // [hd][kv], padded
  __shared__ __align__(16) ushort Pl[4][16 * 72];  // per-wave P

  const int tid = threadIdx.x, l = tid & 63, w = tid >> 6;
  const int lr = l & 15, lk = l >> 4;
  const int p = blockIdx.x, bh = blockIdx.y;
  const int b = bh >> 4, h = bh & 15;
  const int qA0 = p * 64, qB0 = (31 - p) * 64;

  const ushort* Qbh = Q + (size_t)bh * 2048 * 64;
  const ushort* Kbh = K + (size_t)bh * 2048 * 64;
  const ushort* Vbh = V + (size_t)bh * 2048 * 64;

  const int qrA = qA0 + w*16 + lr, qrB = qB0 + w*16 + lr;
  short8 aqA0 = *(const short8*)(Qbh + (size_t)qrA * 64 + lk*8);
  short8 aqA1 = *(const short8*)(Qbh + (size_t)qrA * 64 + 32 + lk*8);
  short8 aqB0 = *(const short8*)(Qbh + (size_t)qrB * 64 + lk*8);
  short8 aqB1 = *(const short8*)(Qbh + (size_t)qrB * 64 + 32 + lk*8);

  floatx4 oA[4] = {}, oB[4] = {};
  float mA[4] = {-1e30f,-1e30f,-1e30f,-1e30f}, lA[4] = {};
  float mB[4] = {-1e30f,-1e30f,-1e30f,-1e30f}, lB[4] = {};

  // K staging (gld16): lane covers row c*8+(l>>3), chunk l&7; source chunk
  // pre-XORed with row&7 so the swizzled read below inverts it.
  const int krow = l >> 3;
  const int kcol = ((l & 7) ^ krow) * 8;
  // V staging (register transpose, round-1-proven)
  const int sr = tid >> 2, sc = (tid & 3) * 16;

  const int kend = 31 - p;
  const int amb = b * 2048;
  int kv0 = 0;

  auto process = [&](const short8& q0f, const short8& q1f, floatx4* o,
                     float* mm, float* ll, int qbase, bool diag) {
    floatx4 sa[4] = {};
    #pragma unroll
    for (int f = 0; f < 4; f++) {
      const int rb = f*16 + lr;
      const int cs = (rb & 7) * 8;
      short8 b0 = *(const short8*)&Kl[rb*64 + ((lk*8) ^ cs)];
      short8 b1 = *(const short8*)&Kl[rb*64 + (((4+lk)*8) ^ cs)];
      sa[f] = __builtin_amdgcn_mfma_f32_16x16x32_bf16(q0f, b0, sa[f], 0,0,0);
      sa[f] = __builtin_amdgcn_mfma_f32_16x16x32_bf16(q1f, b1, sa[f], 0,0,0);
    }
    #pragma unroll
    for (int f = 0; f < 4; f++) {
      const int kv = kv0 + f*16 + lr;
      const bool kvalid = amask[amb + kv] != 0;
      #pragma unroll
      for (int r = 0; r < 4; r++) {
        const int qq = qbase + w*16 + lk*4 + r;
        if (!kvalid || (diag && kv > qq)) sa[f][r] = -1e30f;
      }
    }
    float scl[4];
    #pragma unroll
    for (int r = 0; r < 4; r++) {
      float mx = fmaxf(fmaxf(sa[0][r], sa[1][r]), fmaxf(sa[2][r], sa[3][r]));
      mx = fmaxf(mx, __shfl_xor(mx, 1, 64));
      mx = fmaxf(mx, __shfl_xor(mx, 2, 64));
      mx = fmaxf(mx, __shfl_xor(mx, 4, 64));
      mx = fmaxf(mx, __shfl_xor(mx, 8, 64));
      const float mnew = fmaxf(mm[r], mx);
      scl[r] = exp2f((mm[r] - mnew) * LOG2E);
      mm[r] = mnew;
    }
    float rsum[4] = {};
    #pragma unroll
    for (int f = 0; f < 4; f++)
      #pragma unroll
      for (int r = 0; r < 4; r++) {
        float pv = exp2f((sa[f][r] - mm[r]) * LOG2E);
        sa[f][r] = pv;
        rsum[r] += pv;
      }
    #pragma unroll
    for (int r = 0; r < 4; r++) {
      rsum[r] += __shfl_xor(rsum[r], 1, 64);
      rsum[r] += __shfl_xor(rsum[r], 2, 64);
      rsum[r] += __shfl_xor(rsum[r], 4, 64);
      rsum[r] += __shfl_xor(rsum[r], 8, 64);
      ll[r] = ll[r] * scl[r] + rsum[r];
    }
    #pragma unroll
    for (int f = 0; f < 4; f++)
      #pragma unroll
      for (int r = 0; r < 4; r++) o[f][r] *= scl[r];

    // P -> per-wave LDS; wave-local exchange: waitcnt + sched fence, no barrier
    #pragma unroll
    for (int f = 0; f < 4; f++)
      #pragma unroll
      for (int r = 0; r < 4; r++)
        Pl[w][(lk*4 + r) * 72 + f*16 + lr] = f2bf(sa[f][r]);
    asm volatile("s_waitcnt lgkmcnt(0)" ::: "memory");
    __builtin_amdgcn_sched_barrier(0);
    short8 ap0 = *(const short8*)&Pl[w][lr*72 + lk*8];
    short8 ap1 = *(const short8*)&Pl[w][lr*72 + 32 + lk*8];
    #pragma unroll
    for (int f = 0; f < 4; f++) {
      short8 bv0 = *(const short8*)&Vt[(f*16 + lr) * 72 + lk*8];
      short8 bv1 = *(const short8*)&Vt[(f*16 + lr) * 72 + 32 + lk*8];
      o[f] = __builtin_amdgcn_mfma_f32_16x16x32_bf16(ap0, bv0, o[f], 0,0,0);
      o[f] = __builtin_amdgcn_mfma_f32_16x16x32_bf16(ap1, bv1, o[f], 0,0,0);
    }
  };

  for (int t = 0; t <= kend; t++) {
    kv0 = t * 64;
    __syncthreads();
    #pragma unroll
    for (int i = 0; i < 2; i++) {
      const int c = w*2 + i;
      gld16(Kbh + (size_t)(kv0 + c*8 + krow) * 64 + kcol, &Kl[c*512]);
    }
    {
      const ushort* vs = Vbh + (size_t)(kv0 + sr) * 64 + sc;
      ushort vv[16];
      ((uint4*)vv)[0] = ((const uint4*)vs)[0];
      ((uint4*)vv)[1] = ((const uint4*)vs)[1];
      #pragma unroll
      for (int i = 0; i < 16; i++) Vt[(sc + i) * 72 + sr] = vv[i];
    }
    __syncthreads();
    process(aqB0, aqB1, oB, mB, lB, qB0, t == kend);
    if (t <= p) process(aqA0, aqA1, oA, mA, lA, qA0, t == p);
  }

  #pragma unroll
  for (int r = 0; r < 4; r++) {
    const float invA = lA[r] > 0.f ? 1.0f / lA[r] : 0.f;
    const float invB = lB[r] > 0.f ? 1.0f / lB[r] : 0.f;
    const int sA = qA0 + w*16 + lk*4 + r;
    const int sB = qB0 + w*16 + lk*4 + r;
    const size_t baseA = ((size_t)b * 2048 + sA) * 1024 + h * 64;
    const size_t baseB = ((size_t)b * 2048 + sB) * 1024 + h * 64;
    #pragma unroll
    for (int f = 0; f < 4; f++) {
      AO[baseA + f*16 + lr] = f2bf(oA[f][r] * invA);
      AO[baseB + f*16 + lr] = f2bf(oB[f][r] * invB);
    }
  }
}

extern "C" void kernel_launch(void* const* d_in, const int* in_sizes, int n_in,
                              void* d_out, int out_size, void* d_ws, size_t ws_size,
                              hipStream_t stream) {
  const float* x     = (const float*)d_in[0];
  const int*   amask = (const int*)d_in[1];
  const float* Wq    = (const float*)d_in[2];
  const float* Wk    = (const float*)d_in[3];
  const float* Wv    = (const float*)d_in[4];
  const float* Wo    = (const float*)d_in[5];
  float* out = (float*)d_out;

  const size_t NEL = (size_t)4 * 2048 * 1024;   // 8,388,608 elems (16 MB bf16)
  const size_t WEL = (size_t)1024 * 1024;       // 2 MB bf16

  dim3 blk(256);
  const bool prepped = ws_size >= (size_t)76 * 1024 * 1024;

  if (prepped) {
    ushort* Xb  = (ushort*)d_ws;
    ushort* Wtq = Xb + NEL;
    ushort* Wtk = Wtq + WEL;
    ushort* Wtv = Wtk + WEL;
    ushort* Wto = Wtv + WEL;
    ushort* Qb  = Wto + WEL;
    ushort* Kb  = Qb + NEL;
    ushort* Vb  = Kb + NEL;
    ushort* AO  = Xb;  // Xb dead after k_proj

    k_prep_x<<<4096, blk, 0, stream>>>(x, Xb);
    k_prep_wt<<<dim3(16, 16, 4), blk, 0, stream>>>(Wq, Wk, Wv, Wo,
                                                   Wtq, Wtk, Wtv, Wto);
    k_proj<true><<<dim3(8, 64, 3), blk, 0, stream>>>(
        Xb, Wtq, Wtk, Wtv, nullptr, nullptr, nullptr, Qb, Kb, Vb);
    k_attn<<<dim3(16, 64), blk, 0, stream>>>(Qb, Kb, Vb, amask, AO);
    k_out<true><<<dim3(8, 64), blk, 0, stream>>>(AO, Wto, nullptr, out);
  } else {
    ushort* Xb = (ushort*)d_ws;
    ushort* Qb = Xb + NEL;
    ushort* Kb = Qb + NEL;
    ushort* Vb = Kb + NEL;
    ushort* AO = Xb;

    k_prep_x<<<4096, blk, 0, stream>>>(x, Xb);
    k_proj<false><<<dim3(8, 64, 3), blk, 0, stream>>>(
        Xb, nullptr, nullptr, nullptr, Wq, Wk, Wv, Qb, Kb, Vb);
    k_attn<<<dim3(16, 64), blk, 0, stream>>>(Qb, Kb, Vb, amask, AO);
    k_out<false><<<dim3(8, 64), blk, 0, stream>>>(AO, nullptr, Wo, out);
  }
}

// Round 4
// 363.635 us; speedup vs baseline: 1.7121x; 1.0414x over previous
//
#include <hip/hip_runtime.h>

typedef __attribute__((ext_vector_type(8))) short short8;
typedef __attribute__((ext_vector_type(4))) float floatx4;
typedef __attribute__((address_space(3))) void lvoid;
typedef const __attribute__((address_space(1))) void gvoid;

#define LOG2E 1.44269504088896340736f

__device__ __forceinline__ ushort f2bf(float f) {
  union { float f; unsigned u; } v; v.f = f;
  unsigned r = v.u + 0x7fffu + ((v.u >> 16) & 1u);
  return (ushort)(r >> 16);
}

__device__ __forceinline__ void gld16(const void* g, void* l) {
  __builtin_amdgcn_global_load_lds((gvoid*)g, (lvoid*)l, 16, 0, 0);
}

// ---------------- prep: X fp32 -> bf16 -------------------------------------
__global__ __launch_bounds__(256) void k_prep_x(const float* __restrict__ X,
                                                ushort* __restrict__ Xb) {
  const size_t i = ((size_t)blockIdx.x * 256 + threadIdx.x) * 8;
  float4 v0 = *(const float4*)(X + i);
  float4 v1 = *(const float4*)(X + i + 4);
  ushort u[8] = {f2bf(v0.x), f2bf(v0.y), f2bf(v0.z), f2bf(v0.w),
                 f2bf(v1.x), f2bf(v1.y), f2bf(v1.z), f2bf(v1.w)};
  *(uint4*)(Xb + i) = *(uint4*)u;
}

// ---------------- prep: W fp32 [K][N] -> bf16 transposed [N][K] ------------
__global__ __launch_bounds__(256) void k_prep_wt(
    const float* __restrict__ W0, const float* __restrict__ W1,
    const float* __restrict__ W2, const float* __restrict__ W3,
    ushort* __restrict__ T0, ushort* __restrict__ T1,
    ushort* __restrict__ T2, ushort* __restrict__ T3) {
  __shared__ ushort T[64][66];
  const int z = blockIdx.z;
  const float* W = z == 0 ? W0 : (z == 1 ? W1 : (z == 2 ? W2 : W3));
  ushort* Wt = z == 0 ? T0 : (z == 1 ? T1 : (z == 2 ? T2 : T3));
  const int kb = blockIdx.x * 64, nb = blockIdx.y * 64;
  const int t = threadIdx.x, r = t >> 2, c0 = (t & 3) * 16;
  const float* src = W + (size_t)(kb + r) * 1024 + nb + c0;
  #pragma unroll
  for (int i = 0; i < 4; i++) {
    float4 a = ((const float4*)src)[i];
    T[r][c0 + i*4 + 0] = f2bf(a.x); T[r][c0 + i*4 + 1] = f2bf(a.y);
    T[r][c0 + i*4 + 2] = f2bf(a.z); T[r][c0 + i*4 + 3] = f2bf(a.w);
  }
  __syncthreads();
  ushort u[16];
  #pragma unroll
  for (int j = 0; j < 16; j++) u[j] = T[c0 + j][r];
  ushort* dst = Wt + (size_t)(nb + r) * 1024 + kb + c0;
  ((uint4*)dst)[0] = ((uint4*)u)[0];
  ((uint4*)dst)[1] = ((uint4*)u)[1];
}

// ---------------- GEMM loop (macro, templated B staging) -------------------
#define GEMM_LOOP(Aptr, BTptr, BFptr)                                          \
  constexpr int LDB = PREPPED ? 32 : 40;                                       \
  __shared__ __align__(16) ushort As[128 * 32];                                \
  __shared__ __align__(16) ushort Bs[128 * LDB];                               \
  const int tid = threadIdx.x, l = tid & 63, w = tid >> 6;                     \
  const int wm = w >> 1, wn = w & 1, lr = l & 15, lk = l >> 4;                 \
  const int m0 = blockIdx.y * 128, n0 = blockIdx.x * 128;                      \
  const int srow = l >> 2;                                                     \
  const int scol = ((l & 3) ^ ((l >> 3) & 3)) * 8;                             \
  const int c0 = w * 2;                                                        \
  const int xchunk = (lk ^ ((lr >> 1) & 3)) * 8;                               \
  const int bk = tid >> 3, bn = (tid & 7) * 16;                                \
  floatx4 acc[4][4] = {};                                                      \
  for (int kt = 0; kt < 1024; kt += 32) {                                      \
    __syncthreads();                                                           \
    _Pragma("unroll")                                                          \
    for (int i = 0; i < 2; i++) {                                              \
      const int c = c0 + i;                                                    \
      gld16(Aptr + (size_t)(m0 + c*16 + srow) * 1024 + kt + scol, &As[c*512]); \
      if constexpr (PREPPED)                                                   \
        gld16(BTptr + (size_t)(n0 + c*16 + srow) * 1024 + kt + scol,           \
              &Bs[c*512]);                                                     \
    }                                                                          \
    if constexpr (!PREPPED) {                                                  \
      const float* src = BFptr + (size_t)(kt + bk) * 1024 + n0 + bn;           \
      float vb[16];                                                            \
      _Pragma("unroll")                                                        \
      for (int i = 0; i < 4; i++) ((float4*)vb)[i] = ((const float4*)src)[i];  \
      _Pragma("unroll")                                                        \
      for (int i = 0; i < 16; i++) Bs[(bn + i) * 40 + bk] = f2bf(vb[i]);       \
    }                                                                          \
    __syncthreads();                                                           \
    short8 af[4], bfr[4];                                                      \
    _Pragma("unroll")                                                          \
    for (int f = 0; f < 4; f++) {                                              \
      af[f] = *(const short8*)&As[(wm*64 + f*16 + lr) * 32 + xchunk];          \
      if constexpr (PREPPED)                                                   \
        bfr[f] = *(const short8*)&Bs[(wn*64 + f*16 + lr) * 32 + xchunk];       \
      else                                                                     \
        bfr[f] = *(const short8*)&Bs[(wn*64 + f*16 + lr) * 40 + lk*8];         \
    }                                                                          \
    _Pragma("unroll")                                                          \
    for (int i = 0; i < 4; i++)                                                \
      _Pragma("unroll")                                                        \
      for (int j = 0; j < 4; j++)                                              \
        acc[i][j] = __builtin_amdgcn_mfma_f32_16x16x32_bf16(af[i], bfr[j],     \
                                                            acc[i][j], 0,0,0);\
  }

// Projection GEMM. z=0: Q (scaled 1/8, [b,h,s,hd]); z=1: K ([b,h,s,hd]);
// z=2: V written TRANSPOSED [b,h,hd,s].
template <bool PREPPED>
__global__ __launch_bounds__(256) void k_proj(
    const ushort* __restrict__ Xb,
    const ushort* __restrict__ Wtq, const ushort* __restrict__ Wtk,
    const ushort* __restrict__ Wtv,
    const float* __restrict__ Wfq, const float* __restrict__ Wfk,
    const float* __restrict__ Wfv,
    ushort* __restrict__ Qo, ushort* __restrict__ Ko, ushort* __restrict__ Vo)
{
  const int z = blockIdx.z;
  const ushort* Bt = PREPPED ? (z == 0 ? Wtq : (z == 1 ? Wtk : Wtv)) : nullptr;
  const float*  Bf = PREPPED ? nullptr : (z == 0 ? Wfq : (z == 1 ? Wfk : Wfv));
  ushort* Out = z == 0 ? Qo : (z == 1 ? Ko : Vo);
  const float scale = z == 0 ? 0.125f : 1.0f;
  GEMM_LOOP(Xb, Bt, Bf)
  if (z == 2) {
    // V: write transposed [bh][hd][s]; 4 consecutive s per 8B store
    #pragma unroll
    for (int i = 0; i < 4; i++) {
      const int m = m0 + wm*64 + i*16 + lk*4;
      const int bb = m >> 11, s = m & 2047;
      #pragma unroll
      for (int j = 0; j < 4; j++) {
        const int n = n0 + wn*64 + j*16 + lr;
        const int h = n >> 6, hd = n & 63;
        ushort u4[4];
        #pragma unroll
        for (int r = 0; r < 4; r++) u4[r] = f2bf(acc[i][j][r]);
        *(uint2*)(Out + (((size_t)(bb*16 + h)) * 64 + hd) * 2048 + s) = *(uint2*)u4;
      }
    }
  } else {
    #pragma unroll
    for (int i = 0; i < 4; i++) {
      #pragma unroll
      for (int j = 0; j < 4; j++) {
        const int n = n0 + wn*64 + j*16 + lr;
        const int h = n >> 6, hd = n & 63;
        #pragma unroll
        for (int r = 0; r < 4; r++) {
          const int m = m0 + wm*64 + i*16 + lk*4 + r;
          const int bb = m >> 11, s = m & 2047;
          Out[(((size_t)(bb*16 + h)) * 2048 + s) * 64 + hd] = f2bf(acc[i][j][r] * scale);
        }
      }
    }
  }
}

// Output GEMM: fp32 out [8192][1024] = AO(bf16) @ Wo
template <bool PREPPED>
__global__ __launch_bounds__(256) void k_out(
    const ushort* __restrict__ A, const ushort* __restrict__ Wt,
    const float* __restrict__ Wf, float* __restrict__ Out)
{
  GEMM_LOOP(A, Wt, Wf)
  #pragma unroll
  for (int i = 0; i < 4; i++) {
    #pragma unroll
    for (int j = 0; j < 4; j++) {
      const int n = n0 + wn*64 + j*16 + lr;
      #pragma unroll
      for (int r = 0; r < 4; r++) {
        const int m = m0 + wm*64 + i*16 + lk*4 + r;
        Out[(size_t)m * 1024 + n] = acc[i][j][r];
      }
    }
  }
}

// ---------------- Flash attention, paired q-tiles {p, 31-p} ----------------
// K [bh][s][64] and V^T [bh][hd][s], both staged via gld16 + XOR swizzle.
// XCD-aware block swizzle: each XCD owns 8 consecutive bh.
__global__ __launch_bounds__(256) void k_attn(
    const ushort* __restrict__ Q, const ushort* __restrict__ K,
    const ushort* __restrict__ V, const int* __restrict__ amask,
    ushort* __restrict__ AO)
{
  __shared__ __align__(16) ushort Kl[64 * 64];     // XOR-swizzled
  __shared__ __align__(16) ushort Vl[64 * 64];     // V^T tile, XOR-swizzled
  __shared__ __align__(16) ushort Pl[4][16 * 72];  // per-wave P

  const int tid = threadIdx.x, l = tid & 63, w = tid >> 6;
  const int lr = l & 15, lk = l >> 4;
  const int g = blockIdx.x;
  const int swz = (g & 7) * 128 + (g >> 3);        // bijective XCD chunking
  const int p = swz & 15, bh = swz >> 4;
  const int b = bh >> 4, h = bh & 15;
  const int qA0 = p * 64, qB0 = (31 - p) * 64;

  const ushort* Qbh = Q + (size_t)bh * 2048 * 64;
  const ushort* Kbh = K + (size_t)bh * 2048 * 64;
  const ushort* Vbh = V + (size_t)bh * 64 * 2048;  // transposed [hd][s]

  const int qrA = qA0 + w*16 + lr, qrB = qB0 + w*16 + lr;
  short8 aqA0 = *(const short8*)(Qbh + (size_t)qrA * 64 + lk*8);
  short8 aqA1 = *(const short8*)(Qbh + (size_t)qrA * 64 + 32 + lk*8);
  short8 aqB0 = *(const short8*)(Qbh + (size_t)qrB * 64 + lk*8);
  short8 aqB1 = *(const short8*)(Qbh + (size_t)qrB * 64 + 32 + lk*8);

  floatx4 oA[4] = {}, oB[4] = {};
  float mA[4] = {-1e30f,-1e30f,-1e30f,-1e30f}, lA[4] = {};
  float mB[4] = {-1e30f,-1e30f,-1e30f,-1e30f}, lB[4] = {};

  // staging lane addresses (chunk-XOR swizzled source)
  const int krow = l >> 3;
  const int kcol = ((l & 7) ^ krow) * 8;

  const int kend = 31 - p;
  const int amb = b * 2048;
  int kv0 = 0;

  auto process = [&](const short8& q0f, const short8& q1f, floatx4* o,
                     float* mm, float* ll, int qbase, bool diag,
                     const float* kadd) {
    floatx4 sa[4] = {};
    #pragma unroll
    for (int f = 0; f < 4; f++) {
      const int rb = f*16 + lr;
      const int cs = (rb & 7) * 8;
      short8 b0 = *(const short8*)&Kl[rb*64 + ((lk*8) ^ cs)];
      short8 b1 = *(const short8*)&Kl[rb*64 + (((4+lk)*8) ^ cs)];
      sa[f] = __builtin_amdgcn_mfma_f32_16x16x32_bf16(q0f, b0, sa[f], 0,0,0);
      sa[f] = __builtin_amdgcn_mfma_f32_16x16x32_bf16(q1f, b1, sa[f], 0,0,0);
    }
    #pragma unroll
    for (int f = 0; f < 4; f++) {
      const int kv = kv0 + f*16 + lr;
      #pragma unroll
      for (int r = 0; r < 4; r++) {
        sa[f][r] += kadd[f];
        if (diag) {
          const int qq = qbase + w*16 + lk*4 + r;
          if (kv > qq) sa[f][r] = -1e30f;
        }
      }
    }
    float scl[4];
    #pragma unroll
    for (int r = 0; r < 4; r++) {
      float mx = fmaxf(fmaxf(sa[0][r], sa[1][r]), fmaxf(sa[2][r], sa[3][r]));
      mx = fmaxf(mx, __shfl_xor(mx, 1, 64));
      mx = fmaxf(mx, __shfl_xor(mx, 2, 64));
      mx = fmaxf(mx, __shfl_xor(mx, 4, 64));
      mx = fmaxf(mx, __shfl_xor(mx, 8, 64));
      const float mnew = fmaxf(mm[r], mx);
      scl[r] = exp2f((mm[r] - mnew) * LOG2E);
      mm[r] = mnew;
    }
    float rsum[4] = {};
    #pragma unroll
    for (int f = 0; f < 4; f++)
      #pragma unroll
      for (int r = 0; r < 4; r++) {
        float pv = exp2f((sa[f][r] - mm[r]) * LOG2E);
        sa[f][r] = pv;
        rsum[r] += pv;
      }
    #pragma unroll
    for (int r = 0; r < 4; r++) {
      rsum[r] += __shfl_xor(rsum[r], 1, 64);
      rsum[r] += __shfl_xor(rsum[r], 2, 64);
      rsum[r] += __shfl_xor(rsum[r], 4, 64);
      rsum[r] += __shfl_xor(rsum[r], 8, 64);
      ll[r] = ll[r] * scl[r] + rsum[r];
    }
    #pragma unroll
    for (int f = 0; f < 4; f++)
      #pragma unroll
      for (int r = 0; r < 4; r++) o[f][r] *= scl[r];

    // P -> per-wave LDS via cvt_pk; wave-local sync (rule 18)
    #pragma unroll
    for (int r = 0; r < 4; r++) {
      unsigned pk01, pk23;
      asm("v_cvt_pk_bf16_f32 %0, %1, %2" : "=v"(pk01)
          : "v"(sa[0][r]), "v"(sa[1][r]));
      asm("v_cvt_pk_bf16_f32 %0, %1, %2" : "=v"(pk23)
          : "v"(sa[2][r]), "v"(sa[3][r]));
      ushort* prow = &Pl[w][(lk*4 + r) * 72];
      prow[lr]      = (ushort)pk01;
      prow[16 + lr] = (ushort)(pk01 >> 16);
      prow[32 + lr] = (ushort)pk23;
      prow[48 + lr] = (ushort)(pk23 >> 16);
    }
    asm volatile("s_waitcnt lgkmcnt(0)" ::: "memory");
    __builtin_amdgcn_sched_barrier(0);
    short8 ap0 = *(const short8*)&Pl[w][lr*72 + lk*8];
    short8 ap1 = *(const short8*)&Pl[w][lr*72 + 32 + lk*8];
    #pragma unroll
    for (int f = 0; f < 4; f++) {
      const int rb = f*16 + lr;
      const int cs = (rb & 7) * 8;
      short8 bv0 = *(const short8*)&Vl[rb*64 + ((lk*8) ^ cs)];
      short8 bv1 = *(const short8*)&Vl[rb*64 + (((4+lk)*8) ^ cs)];
      o[f] = __builtin_amdgcn_mfma_f32_16x16x32_bf16(ap0, bv0, o[f], 0,0,0);
      o[f] = __builtin_amdgcn_mfma_f32_16x16x32_bf16(ap1, bv1, o[f], 0,0,0);
    }
  };

  for (int t = 0; t <= kend; t++) {
    kv0 = t * 64;
    float kadd[4];
    #pragma unroll
    for (int f = 0; f < 4; f++)
      kadd[f] = amask[amb + kv0 + f*16 + lr] ? 0.f : -1e30f;
    __syncthreads();
    #pragma unroll
    for (int i = 0; i < 2; i++) {
      const int c = w*2 + i;
      gld16(Kbh + (size_t)(kv0 + c*8 + krow) * 64 + kcol, &Kl[c*512]);
      gld16(Vbh + (size_t)(c*8 + krow) * 2048 + kv0 + kcol, &Vl[c*512]);
    }
    __syncthreads();
    process(aqB0, aqB1, oB, mB, lB, qB0, t == kend, kadd);
    if (t <= p) process(aqA0, aqA1, oA, mA, lA, qA0, t == p, kadd);
  }

  #pragma unroll
  for (int r = 0; r < 4; r++) {
    const float invA = lA[r] > 0.f ? 1.0f / lA[r] : 0.f;
    const float invB = lB[r] > 0.f ? 1.0f / lB[r] : 0.f;
    const int sA = qA0 + w*16 + lk*4 + r;
    const int sB = qB0 + w*16 + lk*4 + r;
    const size_t baseA = ((size_t)b * 2048 + sA) * 1024 + h * 64;
    const size_t baseB = ((size_t)b * 2048 + sB) * 1024 + h * 64;
    #pragma unroll
    for (int f = 0; f < 4; f++) {
      AO[baseA + f*16 + lr] = f2bf(oA[f][r] * invA);
      AO[baseB + f*16 + lr] = f2bf(oB[f][r] * invB);
    }
  }
}

extern "C" void kernel_launch(void* const* d_in, const int* in_sizes, int n_in,
                              void* d_out, int out_size, void* d_ws, size_t ws_size,
                              hipStream_t stream) {
  const float* x     = (const float*)d_in[0];
  const int*   amask = (const int*)d_in[1];
  const float* Wq    = (const float*)d_in[2];
  const float* Wk    = (const float*)d_in[3];
  const float* Wv    = (const float*)d_in[4];
  const float* Wo    = (const float*)d_in[5];
  float* out = (float*)d_out;

  const size_t NEL = (size_t)4 * 2048 * 1024;   // 8,388,608 elems (16 MB bf16)
  const size_t WEL = (size_t)1024 * 1024;       // 2 MB bf16

  dim3 blk(256);
  const bool prepped = ws_size >= (size_t)76 * 1024 * 1024;

  if (prepped) {
    ushort* Xb  = (ushort*)d_ws;
    ushort* Wtq = Xb + NEL;
    ushort* Wtk = Wtq + WEL;
    ushort* Wtv = Wtk + WEL;
    ushort* Wto = Wtv + WEL;
    ushort* Qb  = Wto + WEL;
    ushort* Kb  = Qb + NEL;
    ushort* Vb  = Kb + NEL;
    ushort* AO  = Xb;  // Xb dead after k_proj

    k_prep_x<<<4096, blk, 0, stream>>>(x, Xb);
    k_prep_wt<<<dim3(16, 16, 4), blk, 0, stream>>>(Wq, Wk, Wv, Wo,
                                                   Wtq, Wtk, Wtv, Wto);
    k_proj<true><<<dim3(8, 64, 3), blk, 0, stream>>>(
        Xb, Wtq, Wtk, Wtv, nullptr, nullptr, nullptr, Qb, Kb, Vb);
    k_attn<<<dim3(1024), blk, 0, stream>>>(Qb, Kb, Vb, amask, AO);
    k_out<true><<<dim3(8, 64), blk, 0, stream>>>(AO, Wto, nullptr, out);
  } else {
    ushort* Xb = (ushort*)d_ws;
    ushort* Qb = Xb + NEL;
    ushort* Kb = Qb + NEL;
    ushort* Vb = Kb + NEL;
    ushort* AO = Xb;

    k_prep_x<<<4096, blk, 0, stream>>>(x, Xb);
    k_proj<false><<<dim3(8, 64, 3), blk, 0, stream>>>(
        Xb, nullptr, nullptr, nullptr, Wq, Wk, Wv, Qb, Kb, Vb);
    k_attn<<<dim3(1024), blk, 0, stream>>>(Qb, Kb, Vb, amask, AO);
    k_out<false><<<dim3(8, 64), blk, 0, stream>>>(AO, nullptr, Wo, out);
  }
}

// Round 6
// 309.851 us; speedup vs baseline: 2.0093x; 1.1736x over previous
//
#include <hip/hip_runtime.h>

typedef __attribute__((ext_vector_type(8))) short short8;
typedef __attribute__((ext_vector_type(4))) float floatx4;
typedef __attribute__((address_space(3))) void lvoid;
typedef const __attribute__((address_space(1))) void gvoid;

#define LOG2E 1.44269504088896340736f

__device__ __forceinline__ ushort f2bf(float f) {
  union { float f; unsigned u; } v; v.f = f;
  unsigned r = v.u + 0x7fffu + ((v.u >> 16) & 1u);
  return (ushort)(r >> 16);
}

__device__ __forceinline__ void gld16(const void* g, void* l) {
  __builtin_amdgcn_global_load_lds((gvoid*)g, (lvoid*)l, 16, 0, 0);
}

// ---------------- prep: X fp32 -> bf16 -------------------------------------
__global__ __launch_bounds__(256) void k_prep_x(const float* __restrict__ X,
                                                ushort* __restrict__ Xb) {
  const size_t i = ((size_t)blockIdx.x * 256 + threadIdx.x) * 8;
  float4 v0 = *(const float4*)(X + i);
  float4 v1 = *(const float4*)(X + i + 4);
  ushort u[8] = {f2bf(v0.x), f2bf(v0.y), f2bf(v0.z), f2bf(v0.w),
                 f2bf(v1.x), f2bf(v1.y), f2bf(v1.z), f2bf(v1.w)};
  *(uint4*)(Xb + i) = *(uint4*)u;
}

// ---------------- prep: W fp32 [K][N] -> bf16 transposed [N][K] ------------
__global__ __launch_bounds__(256) void k_prep_wt(
    const float* __restrict__ W0, const float* __restrict__ W1,
    const float* __restrict__ W2, const float* __restrict__ W3,
    ushort* __restrict__ T0, ushort* __restrict__ T1,
    ushort* __restrict__ T2, ushort* __restrict__ T3) {
  __shared__ ushort T[64][66];
  const int z = blockIdx.z;
  const float* W = z == 0 ? W0 : (z == 1 ? W1 : (z == 2 ? W2 : W3));
  ushort* Wt = z == 0 ? T0 : (z == 1 ? T1 : (z == 2 ? T2 : T3));
  const int kb = blockIdx.x * 64, nb = blockIdx.y * 64;
  const int t = threadIdx.x, r = t >> 2, c0 = (t & 3) * 16;
  const float* src = W + (size_t)(kb + r) * 1024 + nb + c0;
  #pragma unroll
  for (int i = 0; i < 4; i++) {
    float4 a = ((const float4*)src)[i];
    T[r][c0 + i*4 + 0] = f2bf(a.x); T[r][c0 + i*4 + 1] = f2bf(a.y);
    T[r][c0 + i*4 + 2] = f2bf(a.z); T[r][c0 + i*4 + 3] = f2bf(a.w);
  }
  __syncthreads();
  ushort u[16];
  #pragma unroll
  for (int j = 0; j < 16; j++) u[j] = T[c0 + j][r];
  ushort* dst = Wt + (size_t)(nb + r) * 1024 + kb + c0;
  ((uint4*)dst)[0] = ((uint4*)u)[0];
  ((uint4*)dst)[1] = ((uint4*)u)[1];
}

// ---------------- GEMM loop (macro, templated B staging) -------------------
#define GEMM_LOOP(Aptr, BTptr, BFptr)                                          \
  constexpr int LDB = PREPPED ? 32 : 40;                                       \
  __shared__ __align__(16) ushort As[128 * 32];                                \
  __shared__ __align__(16) ushort Bs[128 * LDB];                               \
  const int tid = threadIdx.x, l = tid & 63, w = tid >> 6;                     \
  const int wm = w >> 1, wn = w & 1, lr = l & 15, lk = l >> 4;                 \
  const int m0 = blockIdx.y * 128, n0 = blockIdx.x * 128;                      \
  const int srow = l >> 2;                                                     \
  const int scol = ((l & 3) ^ ((l >> 3) & 3)) * 8;                             \
  const int c0 = w * 2;                                                        \
  const int xchunk = (lk ^ ((lr >> 1) & 3)) * 8;                               \
  const int bk = tid >> 3, bn = (tid & 7) * 16;                                \
  floatx4 acc[4][4] = {};                                                      \
  for (int kt = 0; kt < 1024; kt += 32) {                                      \
    __syncthreads();                                                           \
    _Pragma("unroll")                                                          \
    for (int i = 0; i < 2; i++) {                                              \
      const int c = c0 + i;                                                    \
      gld16(Aptr + (size_t)(m0 + c*16 + srow) * 1024 + kt + scol, &As[c*512]); \
      if constexpr (PREPPED)                                                   \
        gld16(BTptr + (size_t)(n0 + c*16 + srow) * 1024 + kt + scol,           \
              &Bs[c*512]);                                                     \
    }                                                                          \
    if constexpr (!PREPPED) {                                                  \
      const float* src = BFptr + (size_t)(kt + bk) * 1024 + n0 + bn;           \
      float vb[16];                                                            \
      _Pragma("unroll")                                                        \
      for (int i = 0; i < 4; i++) ((float4*)vb)[i] = ((const float4*)src)[i];  \
      _Pragma("unroll")                                                        \
      for (int i = 0; i < 16; i++) Bs[(bn + i) * 40 + bk] = f2bf(vb[i]);       \
    }                                                                          \
    __syncthreads();                                                           \
    short8 af[4], bfr[4];                                                      \
    _Pragma("unroll")                                                          \
    for (int f = 0; f < 4; f++) {                                              \
      af[f] = *(const short8*)&As[(wm*64 + f*16 + lr) * 32 + xchunk];          \
      if constexpr (PREPPED)                                                   \
        bfr[f] = *(const short8*)&Bs[(wn*64 + f*16 + lr) * 32 + xchunk];       \
      else                                                                     \
        bfr[f] = *(const short8*)&Bs[(wn*64 + f*16 + lr) * 40 + lk*8];         \
    }                                                                          \
    _Pragma("unroll")                                                          \
    for (int i = 0; i < 4; i++)                                                \
      _Pragma("unroll")                                                        \
      for (int j = 0; j < 4; j++)                                              \
        acc[i][j] = __builtin_amdgcn_mfma_f32_16x16x32_bf16(af[i], bfr[j],     \
                                                            acc[i][j], 0,0,0);\
  }

// Projection GEMM. z=0: Q (scaled 1/8, [b,h,s,hd]); z=1: K ([b,h,s,hd]);
// z=2: V written TRANSPOSED [b,h,hd,s].
template <bool PREPPED>
__global__ __launch_bounds__(256) void k_proj(
    const ushort* __restrict__ Xb,
    const ushort* __restrict__ Wtq, const ushort* __restrict__ Wtk,
    const ushort* __restrict__ Wtv,
    const float* __restrict__ Wfq, const float* __restrict__ Wfk,
    const float* __restrict__ Wfv,
    ushort* __restrict__ Qo, ushort* __restrict__ Ko, ushort* __restrict__ Vo)
{
  const int z = blockIdx.z;
  const ushort* Bt = PREPPED ? (z == 0 ? Wtq : (z == 1 ? Wtk : Wtv)) : nullptr;
  const float*  Bf = PREPPED ? nullptr : (z == 0 ? Wfq : (z == 1 ? Wfk : Wfv));
  ushort* Out = z == 0 ? Qo : (z == 1 ? Ko : Vo);
  const float scale = z == 0 ? 0.125f : 1.0f;
  GEMM_LOOP(Xb, Bt, Bf)
  if (z == 2) {
    // V: write transposed [bh][hd][s]; 4 consecutive s per 8B store
    #pragma unroll
    for (int i = 0; i < 4; i++) {
      const int m = m0 + wm*64 + i*16 + lk*4;
      const int bb = m >> 11, s = m & 2047;
      #pragma unroll
      for (int j = 0; j < 4; j++) {
        const int n = n0 + wn*64 + j*16 + lr;
        const int h = n >> 6, hd = n & 63;
        ushort u4[4];
        #pragma unroll
        for (int r = 0; r < 4; r++) u4[r] = f2bf(acc[i][j][r]);
        *(uint2*)(Out + (((size_t)(bb*16 + h)) * 64 + hd) * 2048 + s) = *(uint2*)u4;
      }
    }
  } else {
    #pragma unroll
    for (int i = 0; i < 4; i++) {
      #pragma unroll
      for (int j = 0; j < 4; j++) {
        const int n = n0 + wn*64 + j*16 + lr;
        const int h = n >> 6, hd = n & 63;
        #pragma unroll
        for (int r = 0; r < 4; r++) {
          const int m = m0 + wm*64 + i*16 + lk*4 + r;
          const int bb = m >> 11, s = m & 2047;
          Out[(((size_t)(bb*16 + h)) * 2048 + s) * 64 + hd] = f2bf(acc[i][j][r] * scale);
        }
      }
    }
  }
}

// Output GEMM: fp32 out [8192][1024] = AO(bf16) @ Wo
template <bool PREPPED>
__global__ __launch_bounds__(256) void k_out(
    const ushort* __restrict__ A, const ushort* __restrict__ Wt,
    const float* __restrict__ Wf, float* __restrict__ Out)
{
  GEMM_LOOP(A, Wt, Wf)
  #pragma unroll
  for (int i = 0; i < 4; i++) {
    #pragma unroll
    for (int j = 0; j < 4; j++) {
      const int n = n0 + wn*64 + j*16 + lr;
      #pragma unroll
      for (int r = 0; r < 4; r++) {
        const int m = m0 + wm*64 + i*16 + lk*4 + r;
        Out[(size_t)m * 1024 + n] = acc[i][j][r];
      }
    }
  }
}

// ---------------- Flash attention, paired q-tiles {p, 31-p} ----------------
// Swapped QK^T (S^T layout): per-lane softmax for one q-row. K [bh][s][64],
// V^T [bh][hd][s], both via gld16 + XOR swizzle. XCD-aware block swizzle.
__global__ __launch_bounds__(256) void k_attn(
    const ushort* __restrict__ Q, const ushort* __restrict__ K,
    const ushort* __restrict__ V, const int* __restrict__ amask,
    ushort* __restrict__ AO)
{
  __shared__ __align__(16) ushort Kl[64 * 64];     // XOR-swizzled
  __shared__ __align__(16) ushort Vl[64 * 64];     // V^T tile, XOR-swizzled
  __shared__ __align__(16) ushort Pl[4][16 * 72];  // per-wave P [q][kv]

  const int tid = threadIdx.x, l = tid & 63, w = tid >> 6;
  const int lr = l & 15, lk = l >> 4;
  const int g = blockIdx.x;
  const int swz = (g & 7) * 128 + (g >> 3);        // bijective XCD chunking
  const int p = swz & 15, bh = swz >> 4;
  const int b = bh >> 4, h = bh & 15;
  const int qA0 = p * 64, qB0 = (31 - p) * 64;

  const ushort* Qbh = Q + (size_t)bh * 2048 * 64;
  const ushort* Kbh = K + (size_t)bh * 2048 * 64;
  const ushort* Vbh = V + (size_t)bh * 64 * 2048;  // transposed [hd][s]

  const int qrA = qA0 + w*16 + lr, qrB = qB0 + w*16 + lr;
  short8 aqA0 = *(const short8*)(Qbh + (size_t)qrA * 64 + lk*8);
  short8 aqA1 = *(const short8*)(Qbh + (size_t)qrA * 64 + 32 + lk*8);
  short8 aqB0 = *(const short8*)(Qbh + (size_t)qrB * 64 + lk*8);
  short8 aqB1 = *(const short8*)(Qbh + (size_t)qrB * 64 + 32 + lk*8);

  floatx4 oA[4] = {}, oB[4] = {};
  float mmA = -1e30f, llA = 0.f, mmB = -1e30f, llB = 0.f;

  // staging lane addresses (chunk-XOR swizzled source)
  const int krow = l >> 3;
  const int kcol = ((l & 7) ^ krow) * 8;

  const int kend = 31 - p;
  const int amb = b * 2048;
  int kv0 = 0;

  // per-lane softmax state: lane (lr,lk) owns q-row = base + w*16 + lr
  // (all 4 lk-lanes sharing lr evolve identical state after shfl reduces)
  auto process = [&](const short8& q0f, const short8& q1f, floatx4* o,
                     float& mm, float& ll, int qbase, bool diag,
                     float mval, bool allv) {
    // S^T = K Q^T: sa[f][r] = S[q = qbase+w*16+lr][kv = kv0 + f*16 + lk*4 + r]
    floatx4 sa[4] = {};
    #pragma unroll
    for (int f = 0; f < 4; f++) {
      const int rb = f*16 + lr;
      const int cs = (rb & 7) * 8;
      short8 k0 = *(const short8*)&Kl[rb*64 + ((lk*8) ^ cs)];
      short8 k1 = *(const short8*)&Kl[rb*64 + (((4+lk)*8) ^ cs)];
      sa[f] = __builtin_amdgcn_mfma_f32_16x16x32_bf16(k0, q0f, sa[f], 0,0,0);
      sa[f] = __builtin_amdgcn_mfma_f32_16x16x32_bf16(k1, q1f, sa[f], 0,0,0);
    }
    // key mask: rare non-uniform path only
    if (!allv) {
      #pragma unroll
      for (int f = 0; f < 4; f++)
        #pragma unroll
        for (int r = 0; r < 4; r++)
          sa[f][r] += __shfl(mval, f*16 + lk*4 + r, 64);
    }
    // causal: only on diagonal tile
    if (diag) {
      const int q = qbase + w*16 + lr;
      #pragma unroll
      for (int f = 0; f < 4; f++)
        #pragma unroll
        for (int r = 0; r < 4; r++)
          if (kv0 + f*16 + lk*4 + r > q) sa[f][r] = -1e30f;
    }
    // row max (one q per lane; combine the 4 lk-lanes sharing lr)
    float mx = sa[0][0];
    #pragma unroll
    for (int f = 0; f < 4; f++)
      #pragma unroll
      for (int r = 0; r < 4; r++) mx = fmaxf(mx, sa[f][r]);
    mx = fmaxf(mx, __shfl_xor(mx, 16, 64));
    mx = fmaxf(mx, __shfl_xor(mx, 32, 64));
    // defer-max (T13): rescale only when max grew past threshold
    if (!__all(mx <= mm + 8.f)) {
      const float pm = fmaxf(mm, mx);
      const float scl = __builtin_exp2f((mm - pm) * LOG2E);
      mm = pm;
      ll *= scl;
      float sclo[4];
      #pragma unroll
      for (int r = 0; r < 4; r++) sclo[r] = __shfl(scl, lk*4 + r, 64);
      #pragma unroll
      for (int f = 0; f < 4; f++)
        #pragma unroll
        for (int r = 0; r < 4; r++) o[f][r] *= sclo[r];
    }
    // P = exp2(S*log2e - mm*log2e), row sum
    const float nm = mm * LOG2E;
    float rs = 0.f;
    #pragma unroll
    for (int f = 0; f < 4; f++)
      #pragma unroll
      for (int r = 0; r < 4; r++) {
        float pv = __builtin_exp2f(__builtin_fmaf(sa[f][r], LOG2E, -nm));
        sa[f][r] = pv;
        rs += pv;
      }
    rs += __shfl_xor(rs, 16, 64);
    rs += __shfl_xor(rs, 32, 64);
    ll += rs;
    // P -> LDS [q][kv]: 4 consecutive kv per fragment -> b64 stores
    #pragma unroll
    for (int f = 0; f < 4; f++) {
      unsigned pk0, pk1;
      asm("v_cvt_pk_bf16_f32 %0, %1, %2" : "=v"(pk0)
          : "v"(sa[f][0]), "v"(sa[f][1]));
      asm("v_cvt_pk_bf16_f32 %0, %1, %2" : "=v"(pk1)
          : "v"(sa[f][2]), "v"(sa[f][3]));
      *(uint2*)&Pl[w][lr*72 + f*16 + lk*4] = make_uint2(pk0, pk1);
    }
    asm volatile("s_waitcnt lgkmcnt(0)" ::: "memory");
    __builtin_amdgcn_sched_barrier(0);
    short8 ap0 = *(const short8*)&Pl[w][lr*72 + lk*8];
    short8 ap1 = *(const short8*)&Pl[w][lr*72 + 32 + lk*8];
    #pragma unroll
    for (int f = 0; f < 4; f++) {
      const int rb = f*16 + lr;
      const int cs = (rb & 7) * 8;
      short8 bv0 = *(const short8*)&Vl[rb*64 + ((lk*8) ^ cs)];
      short8 bv1 = *(const short8*)&Vl[rb*64 + (((4+lk)*8) ^ cs)];
      o[f] = __builtin_amdgcn_mfma_f32_16x16x32_bf16(ap0, bv0, o[f], 0,0,0);
      o[f] = __builtin_amdgcn_mfma_f32_16x16x32_bf16(ap1, bv1, o[f], 0,0,0);
    }
  };

  for (int t = 0; t <= kend; t++) {
    kv0 = t * 64;
    const int am = amask[amb + kv0 + l];
    const bool allv = __all(am != 0);
    const float mval = am ? 0.f : -1e30f;
    __syncthreads();
    #pragma unroll
    for (int i = 0; i < 2; i++) {
      const int c = w*2 + i;
      gld16(Kbh + (size_t)(kv0 + c*8 + krow) * 64 + kcol, &Kl[c*512]);
      gld16(Vbh + (size_t)(c*8 + krow) * 2048 + kv0 + kcol, &Vl[c*512]);
    }
    __syncthreads();
    process(aqB0, aqB1, oB, mmB, llB, qB0, t == kend, mval, allv);
    if (t <= p) process(aqA0, aqA1, oA, mmA, llA, qA0, t == p, mval, allv);
  }

  // epilogue: o rows are q = lk*4+r; fetch inv from the lane owning that q
  const float invA = llA > 0.f ? 1.0f / llA : 0.f;
  const float invB = llB > 0.f ? 1.0f / llB : 0.f;
  float ivA[4], ivB[4];
  #pragma unroll
  for (int r = 0; r < 4; r++) {
    ivA[r] = __shfl(invA, lk*4 + r, 64);
    ivB[r] = __shfl(invB, lk*4 + r, 64);
  }
  #pragma unroll
  for (int r = 0; r < 4; r++) {
    const int sA = qA0 + w*16 + lk*4 + r;
    const int sB = qB0 + w*16 + lk*4 + r;
    const size_t baseA = ((size_t)b * 2048 + sA) * 1024 + h * 64;
    const size_t baseB = ((size_t)b * 2048 + sB) * 1024 + h * 64;
    #pragma unroll
    for (int f = 0; f < 4; f++) {
      AO[baseA + f*16 + lr] = f2bf(oA[f][r] * ivA[r]);
      AO[baseB + f*16 + lr] = f2bf(oB[f][r] * ivB[r]);
    }
  }
}

extern "C" void kernel_launch(void* const* d_in, const int* in_sizes, int n_in,
                              void* d_out, int out_size, void* d_ws, size_t ws_size,
                              hipStream_t stream) {
  const float* x     = (const float*)d_in[0];
  const int*   amask = (const int*)d_in[1];
  const float* Wq    = (const float*)d_in[2];
  const float* Wk    = (const float*)d_in[3];
  const float* Wv    = (const float*)d_in[4];
  const float* Wo    = (const float*)d_in[5];
  float* out = (float*)d_out;

  const size_t NEL = (size_t)4 * 2048 * 1024;   // 8,388,608 elems (16 MB bf16)
  const size_t WEL = (size_t)1024 * 1024;       // 2 MB bf16

  dim3 blk(256);
  const bool prepped = ws_size >= (size_t)76 * 1024 * 1024;

  if (prepped) {
    ushort* Xb  = (ushort*)d_ws;
    ushort* Wtq = Xb + NEL;
    ushort* Wtk = Wtq + WEL;
    ushort* Wtv = Wtk + WEL;
    ushort* Wto = Wtv + WEL;
    ushort* Qb  = Wto + WEL;
    ushort* Kb  = Qb + NEL;
    ushort* Vb  = Kb + NEL;
    ushort* AO  = Xb;  // Xb dead after k_proj

    k_prep_x<<<4096, blk, 0, stream>>>(x, Xb);
    k_prep_wt<<<dim3(16, 16, 4), blk, 0, stream>>>(Wq, Wk, Wv, Wo,
                                                   Wtq, Wtk, Wtv, Wto);
    k_proj<true><<<dim3(8, 64, 3), blk, 0, stream>>>(
        Xb, Wtq, Wtk, Wtv, nullptr, nullptr, nullptr, Qb, Kb, Vb);
    k_attn<<<dim3(1024), blk, 0, stream>>>(Qb, Kb, Vb, amask, AO);
    k_out<true><<<dim3(8, 64), blk, 0, stream>>>(AO, Wto, nullptr, out);
  } else {
    ushort* Xb = (ushort*)d_ws;
    ushort* Qb = Xb + NEL;
    ushort* Kb = Qb + NEL;
    ushort* Vb = Kb + NEL;
    ushort* AO = Xb;

    k_prep_x<<<4096, blk, 0, stream>>>(x, Xb);
    k_proj<false><<<dim3(8, 64, 3), blk, 0, stream>>>(
        Xb, nullptr, nullptr, nullptr, Wq, Wk, Wv, Qb, Kb, Vb);
    k_attn<<<dim3(1024), blk, 0, stream>>>(Qb, Kb, Vb, amask, AO);
    k_out<false><<<dim3(8, 64), blk, 0, stream>>>(AO, nullptr, Wo, out);
  }
}

// Round 7
// 296.836 us; speedup vs baseline: 2.0973x; 1.0438x over previous
//
#include <hip/hip_runtime.h>

typedef __attribute__((ext_vector_type(8))) short short8;
typedef __attribute__((ext_vector_type(4))) float floatx4;
typedef __attribute__((address_space(3))) void lvoid;
typedef const __attribute__((address_space(1))) void gvoid;

#define LOG2E 1.44269504088896340736f

__device__ __forceinline__ ushort f2bf(float f) {
  union { float f; unsigned u; } v; v.f = f;
  unsigned r = v.u + 0x7fffu + ((v.u >> 16) & 1u);
  return (ushort)(r >> 16);
}

__device__ __forceinline__ void gld16(const void* g, void* l) {
  __builtin_amdgcn_global_load_lds((gvoid*)g, (lvoid*)l, 16, 0, 0);
}

// ---------------- prep: X fp32 -> bf16 -------------------------------------
__global__ __launch_bounds__(256) void k_prep_x(const float* __restrict__ X,
                                                ushort* __restrict__ Xb) {
  const size_t i = ((size_t)blockIdx.x * 256 + threadIdx.x) * 8;
  float4 v0 = *(const float4*)(X + i);
  float4 v1 = *(const float4*)(X + i + 4);
  ushort u[8] = {f2bf(v0.x), f2bf(v0.y), f2bf(v0.z), f2bf(v0.w),
                 f2bf(v1.x), f2bf(v1.y), f2bf(v1.z), f2bf(v1.w)};
  *(uint4*)(Xb + i) = *(uint4*)u;
}

// ---------------- prep: W fp32 [K][N] -> bf16 transposed [N][K] ------------
__global__ __launch_bounds__(256) void k_prep_wt(
    const float* __restrict__ W0, const float* __restrict__ W1,
    const float* __restrict__ W2, const float* __restrict__ W3,
    ushort* __restrict__ T0, ushort* __restrict__ T1,
    ushort* __restrict__ T2, ushort* __restrict__ T3) {
  __shared__ ushort T[64][66];
  const int z = blockIdx.z;
  const float* W = z == 0 ? W0 : (z == 1 ? W1 : (z == 2 ? W2 : W3));
  ushort* Wt = z == 0 ? T0 : (z == 1 ? T1 : (z == 2 ? T2 : T3));
  const int kb = blockIdx.x * 64, nb = blockIdx.y * 64;
  const int t = threadIdx.x, r = t >> 2, c0 = (t & 3) * 16;
  const float* src = W + (size_t)(kb + r) * 1024 + nb + c0;
  #pragma unroll
  for (int i = 0; i < 4; i++) {
    float4 a = ((const float4*)src)[i];
    T[r][c0 + i*4 + 0] = f2bf(a.x); T[r][c0 + i*4 + 1] = f2bf(a.y);
    T[r][c0 + i*4 + 2] = f2bf(a.z); T[r][c0 + i*4 + 3] = f2bf(a.w);
  }
  __syncthreads();
  ushort u[16];
  #pragma unroll
  for (int j = 0; j < 16; j++) u[j] = T[c0 + j][r];
  ushort* dst = Wt + (size_t)(nb + r) * 1024 + kb + c0;
  ((uint4*)dst)[0] = ((uint4*)u)[0];
  ((uint4*)dst)[1] = ((uint4*)u)[1];
}

// ---------------- GEMM loop: 2-phase prefetch, double-buffered LDS ---------
#define GEMM_LOOP(Aptr, BTptr, BFptr)                                          \
  constexpr int LDB = PREPPED ? 32 : 40;                                       \
  __shared__ __align__(16) ushort As[2][128 * 32];                             \
  __shared__ __align__(16) ushort Bs[2][128 * LDB];                            \
  const int tid = threadIdx.x, l = tid & 63, w = tid >> 6;                     \
  const int wm = w >> 1, wn = w & 1, lr = l & 15, lk = l >> 4;                 \
  const int m0 = blockIdx.y * 128, n0 = blockIdx.x * 128;                      \
  const int srow = l >> 2;                                                     \
  const int scol = ((l & 3) ^ ((l >> 3) & 3)) * 8;                             \
  const int c0 = w * 2;                                                        \
  const int xchunk = (lk ^ ((lr >> 1) & 3)) * 8;                               \
  const int bk = tid >> 3, bn = (tid & 7) * 16;                                \
  floatx4 acc[4][4] = {};                                                      \
  /* prologue: stage kt=0 into buffer 0 */                                     \
  _Pragma("unroll")                                                            \
  for (int i = 0; i < 2; i++) {                                                \
    const int c = c0 + i;                                                      \
    gld16(Aptr + (size_t)(m0 + c*16 + srow) * 1024 + scol, &As[0][c*512]);     \
    if constexpr (PREPPED)                                                     \
      gld16(BTptr + (size_t)(n0 + c*16 + srow) * 1024 + scol, &Bs[0][c*512]);  \
  }                                                                            \
  if constexpr (!PREPPED) {                                                    \
    const float* src = BFptr + (size_t)bk * 1024 + n0 + bn;                    \
    float vb[16];                                                              \
    _Pragma("unroll")                                                          \
    for (int i = 0; i < 4; i++) ((float4*)vb)[i] = ((const float4*)src)[i];    \
    _Pragma("unroll")                                                          \
    for (int i = 0; i < 16; i++) Bs[0][(bn + i) * 40 + bk] = f2bf(vb[i]);      \
  }                                                                            \
  for (int kt = 0; kt < 1024; kt += 32) {                                      \
    const int cur = (kt >> 5) & 1, nxt = cur ^ 1;                              \
    __syncthreads(); /* buf[cur] staged; prev reads done (lgkm+vm drained) */  \
    float vbn[16];                                                             \
    if (kt + 32 < 1024) {                                                      \
      _Pragma("unroll")                                                        \
      for (int i = 0; i < 2; i++) {                                            \
        const int c = c0 + i;                                                  \
        gld16(Aptr + (size_t)(m0 + c*16 + srow) * 1024 + kt + 32 + scol,       \
              &As[nxt][c*512]);                                                \
        if constexpr (PREPPED)                                                 \
          gld16(BTptr + (size_t)(n0 + c*16 + srow) * 1024 + kt + 32 + scol,    \
                &Bs[nxt][c*512]);                                              \
      }                                                                        \
      if constexpr (!PREPPED) {                                                \
        const float* src = BFptr + (size_t)(kt + 32 + bk) * 1024 + n0 + bn;    \
        _Pragma("unroll")                                                      \
        for (int i = 0; i < 4; i++)                                            \
          ((float4*)vbn)[i] = ((const float4*)src)[i];                         \
      }                                                                        \
    }                                                                          \
    short8 af[4], bfr[4];                                                      \
    _Pragma("unroll")                                                          \
    for (int f = 0; f < 4; f++) {                                              \
      af[f] = *(const short8*)&As[cur][(wm*64 + f*16 + lr) * 32 + xchunk];     \
      if constexpr (PREPPED)                                                   \
        bfr[f] = *(const short8*)&Bs[cur][(wn*64 + f*16 + lr) * 32 + xchunk];  \
      else                                                                     \
        bfr[f] = *(const short8*)&Bs[cur][(wn*64 + f*16 + lr) * 40 + lk*8];    \
    }                                                                          \
    __builtin_amdgcn_s_setprio(1);                                             \
    _Pragma("unroll")                                                          \
    for (int i = 0; i < 4; i++)                                                \
      _Pragma("unroll")                                                        \
      for (int j = 0; j < 4; j++)                                              \
        acc[i][j] = __builtin_amdgcn_mfma_f32_16x16x32_bf16(af[i], bfr[j],     \
                                                            acc[i][j], 0,0,0);\
    __builtin_amdgcn_s_setprio(0);                                             \
    if constexpr (!PREPPED) {                                                  \
      if (kt + 32 < 1024) { /* write-late (T14): vbn ready under MFMA */       \
        _Pragma("unroll")                                                      \
        for (int i = 0; i < 16; i++)                                           \
          Bs[nxt][(bn + i) * 40 + bk] = f2bf(vbn[i]);                          \
      }                                                                        \
    }                                                                          \
  }

// Projection GEMM. z=0: Q (scaled 1/8, [b,h,s,hd]); z=1: K ([b,h,s,hd]);
// z=2: V written TRANSPOSED [b,h,hd,s].
template <bool PREPPED>
__global__ __launch_bounds__(256) void k_proj(
    const ushort* __restrict__ Xb,
    const ushort* __restrict__ Wtq, const ushort* __restrict__ Wtk,
    const ushort* __restrict__ Wtv,
    const float* __restrict__ Wfq, const float* __restrict__ Wfk,
    const float* __restrict__ Wfv,
    ushort* __restrict__ Qo, ushort* __restrict__ Ko, ushort* __restrict__ Vo)
{
  const int z = blockIdx.z;
  const ushort* Bt = PREPPED ? (z == 0 ? Wtq : (z == 1 ? Wtk : Wtv)) : nullptr;
  const float*  Bf = PREPPED ? nullptr : (z == 0 ? Wfq : (z == 1 ? Wfk : Wfv));
  ushort* Out = z == 0 ? Qo : (z == 1 ? Ko : Vo);
  const float scale = z == 0 ? 0.125f : 1.0f;
  GEMM_LOOP(Xb, Bt, Bf)
  if (z == 2) {
    // V: write transposed [bh][hd][s]; 4 consecutive s per 8B store
    #pragma unroll
    for (int i = 0; i < 4; i++) {
      const int m = m0 + wm*64 + i*16 + lk*4;
      const int bb = m >> 11, s = m & 2047;
      #pragma unroll
      for (int j = 0; j < 4; j++) {
        const int n = n0 + wn*64 + j*16 + lr;
        const int h = n >> 6, hd = n & 63;
        ushort u4[4];
        #pragma unroll
        for (int r = 0; r < 4; r++) u4[r] = f2bf(acc[i][j][r]);
        *(uint2*)(Out + (((size_t)(bb*16 + h)) * 64 + hd) * 2048 + s) = *(uint2*)u4;
      }
    }
  } else {
    #pragma unroll
    for (int i = 0; i < 4; i++) {
      #pragma unroll
      for (int j = 0; j < 4; j++) {
        const int n = n0 + wn*64 + j*16 + lr;
        const int h = n >> 6, hd = n & 63;
        #pragma unroll
        for (int r = 0; r < 4; r++) {
          const int m = m0 + wm*64 + i*16 + lk*4 + r;
          const int bb = m >> 11, s = m & 2047;
          Out[(((size_t)(bb*16 + h)) * 2048 + s) * 64 + hd] = f2bf(acc[i][j][r] * scale);
        }
      }
    }
  }
}

// Output GEMM: fp32 out [8192][1024] = AO(bf16) @ Wo
template <bool PREPPED>
__global__ __launch_bounds__(256) void k_out(
    const ushort* __restrict__ A, const ushort* __restrict__ Wt,
    const float* __restrict__ Wf, float* __restrict__ Out)
{
  GEMM_LOOP(A, Wt, Wf)
  #pragma unroll
  for (int i = 0; i < 4; i++) {
    #pragma unroll
    for (int j = 0; j < 4; j++) {
      const int n = n0 + wn*64 + j*16 + lr;
      #pragma unroll
      for (int r = 0; r < 4; r++) {
        const int m = m0 + wm*64 + i*16 + lk*4 + r;
        Out[(size_t)m * 1024 + n] = acc[i][j][r];
      }
    }
  }
}

// ---------------- Flash attention, paired q-tiles {p, 31-p} ----------------
// Swapped QK^T (S^T layout), per-lane softmax. K/V double-buffered with
// 2-phase prefetch: one barrier per tile, stage(t+1) issued under process(t).
// LDS = 2*8K (K) + 2*8K (V) + 8K (P) = 40960 B -> 4 blocks/CU.
__global__ __launch_bounds__(256) void k_attn(
    const ushort* __restrict__ Q, const ushort* __restrict__ K,
    const ushort* __restrict__ V, const int* __restrict__ amask,
    ushort* __restrict__ AO)
{
  __shared__ __align__(16) ushort Kl[2][64 * 64];  // XOR-swizzled
  __shared__ __align__(16) ushort Vl[2][64 * 64];  // V^T tile, XOR-swizzled
  __shared__ __align__(16) ushort Pl[4][16 * 64];  // per-wave P, XOR-swizzled

  const int tid = threadIdx.x, l = tid & 63, w = tid >> 6;
  const int lr = l & 15, lk = l >> 4;
  const int g = blockIdx.x;
  const int swz = (g & 7) * 128 + (g >> 3);        // bijective XCD chunking
  const int p = swz & 15, bh = swz >> 4;
  const int b = bh >> 4, h = bh & 15;
  const int qA0 = p * 64, qB0 = (31 - p) * 64;

  const ushort* Qbh = Q + (size_t)bh * 2048 * 64;
  const ushort* Kbh = K + (size_t)bh * 2048 * 64;
  const ushort* Vbh = V + (size_t)bh * 64 * 2048;  // transposed [hd][s]

  const int qrA = qA0 + w*16 + lr, qrB = qB0 + w*16 + lr;
  short8 aqA0 = *(const short8*)(Qbh + (size_t)qrA * 64 + lk*8);
  short8 aqA1 = *(const short8*)(Qbh + (size_t)qrA * 64 + 32 + lk*8);
  short8 aqB0 = *(const short8*)(Qbh + (size_t)qrB * 64 + lk*8);
  short8 aqB1 = *(const short8*)(Qbh + (size_t)qrB * 64 + 32 + lk*8);

  floatx4 oA[4] = {}, oB[4] = {};
  float mmA = -1e30f, llA = 0.f, mmB = -1e30f, llB = 0.f;

  // staging lane addresses (chunk-XOR swizzled source)
  const int krow = l >> 3;
  const int kcol = ((l & 7) ^ krow) * 8;

  const int kend = 31 - p;
  const int amb = b * 2048;
  int kv0 = 0;

  auto stage = [&](int bi, int kv) {
    #pragma unroll
    for (int i = 0; i < 2; i++) {
      const int c = w*2 + i;
      gld16(Kbh + (size_t)(kv + c*8 + krow) * 64 + kcol, &Kl[bi][c*512]);
      gld16(Vbh + (size_t)(c*8 + krow) * 2048 + kv + kcol, &Vl[bi][c*512]);
    }
  };

  // per-lane softmax: lane (lr,lk) owns q-row = base + w*16 + lr
  auto process = [&](const short8& q0f, const short8& q1f, floatx4* o,
                     float& mm, float& ll, int qbase, bool diag,
                     float mval, bool allv, int cur) {
    // S^T = K Q^T: sa[f][r] = S[q = qbase+w*16+lr][kv = kv0 + f*16 + lk*4 + r]
    floatx4 sa[4] = {};
    __builtin_amdgcn_s_setprio(1);
    #pragma unroll
    for (int f = 0; f < 4; f++) {
      const int rb = f*16 + lr;
      const int cs = (rb & 7) * 8;
      short8 k0 = *(const short8*)&Kl[cur][rb*64 + ((lk*8) ^ cs)];
      short8 k1 = *(const short8*)&Kl[cur][rb*64 + (((4+lk)*8) ^ cs)];
      sa[f] = __builtin_amdgcn_mfma_f32_16x16x32_bf16(k0, q0f, sa[f], 0,0,0);
      sa[f] = __builtin_amdgcn_mfma_f32_16x16x32_bf16(k1, q1f, sa[f], 0,0,0);
    }
    __builtin_amdgcn_s_setprio(0);
    // key mask: rare non-uniform path only
    if (!allv) {
      #pragma unroll
      for (int f = 0; f < 4; f++)
        #pragma unroll
        for (int r = 0; r < 4; r++)
          sa[f][r] += __shfl(mval, f*16 + lk*4 + r, 64);
    }
    // causal: only on diagonal tile
    if (diag) {
      const int q = qbase + w*16 + lr;
      #pragma unroll
      for (int f = 0; f < 4; f++)
        #pragma unroll
        for (int r = 0; r < 4; r++)
          if (kv0 + f*16 + lk*4 + r > q) sa[f][r] = -1e30f;
    }
    // row max (one q per lane; combine 4 lk-lanes sharing lr)
    float mx = sa[0][0];
    #pragma unroll
    for (int f = 0; f < 4; f++)
      #pragma unroll
      for (int r = 0; r < 4; r++) mx = fmaxf(mx, sa[f][r]);
    mx = fmaxf(mx, __shfl_xor(mx, 16, 64));
    mx = fmaxf(mx, __shfl_xor(mx, 32, 64));
    // defer-max (T13)
    if (!__all(mx <= mm + 8.f)) {
      const float pm = fmaxf(mm, mx);
      const float scl = __builtin_exp2f((mm - pm) * LOG2E);
      mm = pm;
      ll *= scl;
      float sclo[4];
      #pragma unroll
      for (int r = 0; r < 4; r++) sclo[r] = __shfl(scl, lk*4 + r, 64);
      #pragma unroll
      for (int f = 0; f < 4; f++)
        #pragma unroll
        for (int r = 0; r < 4; r++) o[f][r] *= sclo[r];
    }
    // P = exp2(S*log2e - mm*log2e), row sum
    const float nm = mm * LOG2E;
    float rs = 0.f;
    #pragma unroll
    for (int f = 0; f < 4; f++)
      #pragma unroll
      for (int r = 0; r < 4; r++) {
        float pv = __builtin_exp2f(__builtin_fmaf(sa[f][r], LOG2E, -nm));
        sa[f][r] = pv;
        rs += pv;
      }
    rs += __shfl_xor(rs, 16, 64);
    rs += __shfl_xor(rs, 32, 64);
    ll += rs;
    // P -> per-wave LDS, chunk-XOR swizzled (store ch = c ^ (lr&7))
    #pragma unroll
    for (int f = 0; f < 4; f++) {
      unsigned pk0, pk1;
      asm("v_cvt_pk_bf16_f32 %0, %1, %2" : "=v"(pk0)
          : "v"(sa[f][0]), "v"(sa[f][1]));
      asm("v_cvt_pk_bf16_f32 %0, %1, %2" : "=v"(pk1)
          : "v"(sa[f][2]), "v"(sa[f][3]));
      const int ch = (f*2 + (lk>>1)) ^ (lr & 7);
      *(uint2*)&Pl[w][lr*64 + ch*8 + (lk&1)*4] = make_uint2(pk0, pk1);
    }
    asm volatile("s_waitcnt lgkmcnt(0)" ::: "memory");
    __builtin_amdgcn_sched_barrier(0);
    short8 ap0 = *(const short8*)&Pl[w][lr*64 + ((lk ^ (lr&7)) * 8)];
    short8 ap1 = *(const short8*)&Pl[w][lr*64 + (((4+lk) ^ (lr&7)) * 8)];
    __builtin_amdgcn_s_setprio(1);
    #pragma unroll
    for (int f = 0; f < 4; f++) {
      const int rb = f*16 + lr;
      const int cs = (rb & 7) * 8;
      short8 bv0 = *(const short8*)&Vl[cur][rb*64 + ((lk*8) ^ cs)];
      short8 bv1 = *(const short8*)&Vl[cur][rb*64 + (((4+lk)*8) ^ cs)];
      o[f] = __builtin_amdgcn_mfma_f32_16x16x32_bf16(ap0, bv0, o[f], 0,0,0);
      o[f] = __builtin_amdgcn_mfma_f32_16x16x32_bf16(ap1, bv1, o[f], 0,0,0);
    }
    __builtin_amdgcn_s_setprio(0);
  };

  stage(0, 0);  // prologue
  for (int t = 0; t <= kend; t++) {
    kv0 = t * 64;
    const int am = amask[amb + kv0 + l];  // issue early; barrier hides latency
    __syncthreads();  // buf[t&1] staged; prev tile's LDS reads done
    if (t < kend) stage((t + 1) & 1, kv0 + 64);
    const bool allv = __all(am != 0);
    const float mval = am ? 0.f : -1e30f;
    const int cur = t & 1;
    process(aqB0, aqB1, oB, mmB, llB, qB0, t == kend, mval, allv, cur);
    if (t <= p) process(aqA0, aqA1, oA, mmA, llA, qA0, t == p, mval, allv, cur);
  }

  // epilogue: o rows are q = lk*4+r; fetch inv from the lane owning that q
  const float invA = llA > 0.f ? 1.0f / llA : 0.f;
  const float invB = llB > 0.f ? 1.0f / llB : 0.f;
  float ivA[4], ivB[4];
  #pragma unroll
  for (int r = 0; r < 4; r++) {
    ivA[r] = __shfl(invA, lk*4 + r, 64);
    ivB[r] = __shfl(invB, lk*4 + r, 64);
  }
  #pragma unroll
  for (int r = 0; r < 4; r++) {
    const int sA = qA0 + w*16 + lk*4 + r;
    const int sB = qB0 + w*16 + lk*4 + r;
    const size_t baseA = ((size_t)b * 2048 + sA) * 1024 + h * 64;
    const size_t baseB = ((size_t)b * 2048 + sB) * 1024 + h * 64;
    #pragma unroll
    for (int f = 0; f < 4; f++) {
      AO[baseA + f*16 + lr] = f2bf(oA[f][r] * ivA[r]);
      AO[baseB + f*16 + lr] = f2bf(oB[f][r] * ivB[r]);
    }
  }
}

extern "C" void kernel_launch(void* const* d_in, const int* in_sizes, int n_in,
                              void* d_out, int out_size, void* d_ws, size_t ws_size,
                              hipStream_t stream) {
  const float* x     = (const float*)d_in[0];
  const int*   amask = (const int*)d_in[1];
  const float* Wq    = (const float*)d_in[2];
  const float* Wk    = (const float*)d_in[3];
  const float* Wv    = (const float*)d_in[4];
  const float* Wo    = (const float*)d_in[5];
  float* out = (float*)d_out;

  const size_t NEL = (size_t)4 * 2048 * 1024;   // 8,388,608 elems (16 MB bf16)
  const size_t WEL = (size_t)1024 * 1024;       // 2 MB bf16

  dim3 blk(256);
  const bool prepped = ws_size >= (size_t)76 * 1024 * 1024;

  if (prepped) {
    ushort* Xb  = (ushort*)d_ws;
    ushort* Wtq = Xb + NEL;
    ushort* Wtk = Wtq + WEL;
    ushort* Wtv = Wtk + WEL;
    ushort* Wto = Wtv + WEL;
    ushort* Qb  = Wto + WEL;
    ushort* Kb  = Qb + NEL;
    ushort* Vb  = Kb + NEL;
    ushort* AO  = Xb;  // Xb dead after k_proj

    k_prep_x<<<4096, blk, 0, stream>>>(x, Xb);
    k_prep_wt<<<dim3(16, 16, 4), blk, 0, stream>>>(Wq, Wk, Wv, Wo,
                                                   Wtq, Wtk, Wtv, Wto);
    k_proj<true><<<dim3(8, 64, 3), blk, 0, stream>>>(
        Xb, Wtq, Wtk, Wtv, nullptr, nullptr, nullptr, Qb, Kb, Vb);
    k_attn<<<dim3(1024), blk, 0, stream>>>(Qb, Kb, Vb, amask, AO);
    k_out<true><<<dim3(8, 64), blk, 0, stream>>>(AO, Wto, nullptr, out);
  } else {
    ushort* Xb = (ushort*)d_ws;
    ushort* Qb = Xb + NEL;
    ushort* Kb = Qb + NEL;
    ushort* Vb = Kb + NEL;
    ushort* AO = Xb;

    k_prep_x<<<4096, blk, 0, stream>>>(x, Xb);
    k_proj<false><<<dim3(8, 64, 3), blk, 0, stream>>>(
        Xb, nullptr, nullptr, nullptr, Wq, Wk, Wv, Qb, Kb, Vb);
    k_attn<<<dim3(1024), blk, 0, stream>>>(Qb, Kb, Vb, amask, AO);
    k_out<false><<<dim3(8, 64), blk, 0, stream>>>(AO, nullptr, Wo, out);
  }
}